// Round 7
// baseline (239.229 us; speedup 1.0000x reference)
//
#include <hip/hip_runtime.h>
#include <math.h>

// Problem constants (fixed by reference)
#define B_ 2
#define S_ 2048
#define E_ 1024
#define H_ 16
#define D_ 64
#define M_ (B_ * S_)
// HEAD_DIM * -0.5 = -32 (faithful source bug) folded with 1/ln2 (exp2-domain
// softmax). Folded into Wk at convert time.
#define SC2 (-46.166241308446828f)

typedef unsigned short u16;
typedef _Float16 f16;
typedef __attribute__((ext_vector_type(8))) _Float16 f16x8;   // 4 VGPRs
typedef __attribute__((ext_vector_type(2))) __fp16 fp16x2_n;  // builtin's native ret type
typedef __attribute__((ext_vector_type(16))) float f32x16;    // 32x32 MFMA acc

static __device__ __forceinline__ f32x16 mfma_h(f16x8 a, f16x8 b, f32x16 c) {
    return __builtin_amdgcn_mfma_f32_32x32x16_f16(a, b, c, 0, 0, 0);
}
static __device__ __forceinline__ u16 f16bits(f16 h) {
    union { f16 h; u16 u; } c; c.h = h; return c.u;
}
static __device__ __forceinline__ unsigned pack2(u16 a, u16 b) {
    return (unsigned)a | ((unsigned)b << 16);
}
// One v_cvt_pkrtz_f16_f32: packs two floats to two fp16 (RTZ; P in [0,1]).
static __device__ __forceinline__ unsigned pkrtz(float a, float b) {
    fp16x2_n h = __builtin_amdgcn_cvt_pkrtz(a, b);
    unsigned u; __builtin_memcpy(&u, &h, 4); return u;
}
#define ROWMAP(r, hh) (((r) & 3) + ((((r) >> 2)) << 3) + ((hh) << 2))

// ============================================================================
// One-shot fp32 -> fp16 hi + lo-residual split. SC2 folded into Wk here.
// fp16 (11-bit mantissa) is what makes the 2-pass attention split safe:
// dropped V-lo term -> logit noise ~0.04 log2 units (bf16 would be 0.58).
// ============================================================================
__global__ __launch_bounds__(256)
void convert_split(const float* __restrict__ x, const float* __restrict__ Wk,
                   const float* __restrict__ Wv, const float* __restrict__ Wo,
                   u16* __restrict__ Xh, u16* __restrict__ Xl,
                   u16* __restrict__ Wkh, u16* __restrict__ Wkl,
                   u16* __restrict__ Wvh, u16* __restrict__ Wvl,
                   u16* __restrict__ Woh, u16* __restrict__ Wol)
{
    const int blk = blockIdx.x;
    const float* src; u16 *dh, *dl; int base; float sc = 1.0f;
    if (blk < 4096)      { src = x;  dh = Xh;  dl = Xl;  base = blk; }
    else if (blk < 5120) { src = Wk; dh = Wkh; dl = Wkl; base = blk - 4096; sc = SC2; }
    else if (blk < 6144) { src = Wv; dh = Wvh; dl = Wvl; base = blk - 5120; }
    else                 { src = Wo; dh = Woh; dl = Wol; base = blk - 6144; }
    const size_t off = ((size_t)base * 256 + threadIdx.x) * 4;
    const float4 v = *(const float4*)(src + off);
    const float f[4] = {v.x * sc, v.y * sc, v.z * sc, v.w * sc};
    u16 h4[4], l4[4];
#pragma unroll
    for (int i = 0; i < 4; ++i) {
        const f16 h = (f16)f[i];
        h4[i] = f16bits(h);
        l4[i] = f16bits((f16)(f[i] - (float)h));
    }
    *(uint2*)(dh + off) = make_uint2(pack2(h4[0], h4[1]), pack2(h4[2], h4[3]));
    *(uint2*)(dl + off) = make_uint2(pack2(l4[0], l4[1]), pack2(l4[2], l4[3]));
}

// ============================================================================
// GEMM C = A @ W^T, 32x32x16 fp16 MFMA, hi/lo fp16 inputs.
// MODE 0: fused K+V projection, 3-pass split (fp32-grade); outputs
//         Kh/Kl (fp16 hi/lo, SC2 pre-folded), Vh (fp16 hi) [B,H,S,D],
//         V-hi transposed Vt [B,H,D,S].
// MODE 1: O @ Wo^T, hi-only, fp32 out [M,E].
// 256 thr / 4 waves; tile 128x128; wave-tile 128m x 64n (mt=4) with 2-way
// K-SPLIT (ws=w>>1) and fp32 merge via LDS. R = 48 MFMA / 16 b128 reads = 3
// -> per iter/CU: MFMA 1536 cyc vs LDS ~1344 -> MFMA-bound (R5 was R=2,
// LDS-bound). ~350 VGPR -> launch_bounds(256,1) (no spill through 450, m08).
// Register-prefetch of tile k+1 during compute on k. Grid (8,32)=256 = 1/CU.
// ============================================================================
#define CSB 1032            // (128+1)*8 u16 chunk stride
#define ARR (4 * CSB)       // one staged array (4 k-subchunks of 8): 4128 u16

template<int MODE>
__global__ __launch_bounds__(256, 1)
void gemm_f(const u16* __restrict__ Ah_, const u16* __restrict__ Al_,
            const u16* __restrict__ B1h_, const u16* __restrict__ B1l_,
            const u16* __restrict__ B2h_, const u16* __restrict__ B2l_,
            u16* __restrict__ Khg, u16* __restrict__ Klg,
            u16* __restrict__ Vhg, u16* __restrict__ Vtg,
            float* __restrict__ Cout)
{
    constexpr int NARR = (MODE == 0 ? 6 : 2);
    __shared__ u16 stage[NARR * ARR];

    const int tid = threadIdx.x;
    const int w = tid >> 6, l31 = tid & 31, hh = (tid >> 5) & 1;
    const int ws = w >> 1;              // k-split half
    const int wn = (w & 1) << 6;        // n-half: 0 or 64
    const int m0 = blockIdx.y * 128, n0 = blockIdx.x * 128;
    const int ch8 = (ws << 1) + hh;     // this wave-half's 8-elem k-subchunk

    // Staging map: row sr = tid>>1 (0..127), chunk pair c0 = (tid&1)*2
    const int sr = tid >> 1, c0 = (tid & 1) << 1;
    const size_t gA = (size_t)(m0 + sr) * E_ + (c0 << 3);
    const size_t gB = (size_t)(n0 + sr) * E_ + (c0 << 3);
    const int lo0 = c0 * CSB + sr * 8;
    const int lo1 = (c0 + 1) * CSB + sr * 8;

    f32x16 acc1[4][2], acc2[4][2];
#pragma unroll
    for (int mt = 0; mt < 4; ++mt)
#pragma unroll
        for (int nt = 0; nt < 2; ++nt)
#pragma unroll
            for (int r = 0; r < 16; ++r) {
                acc1[mt][nt][r] = 0.f;
                if constexpr (MODE == 0) acc2[mt][nt][r] = 0.f;
            }

    f16x8 pf[2 * NARR];
    const u16* gptr[6];
    gptr[0] = Ah_; gptr[1] = Al_; gptr[2] = B1h_;
    gptr[3] = B1l_; gptr[4] = B2h_; gptr[5] = B2l_;

    auto load_tile = [&](int k0) {
#pragma unroll
        for (int a = 0; a < NARR; ++a) {
            const size_t g = ((MODE == 0 && a < 2) || (MODE == 1 && a < 1)) ? gA : gB;
            const u16* p = (MODE == 1 && a == 1) ? B1h_ : gptr[a];
            pf[2 * a + 0] = *(const f16x8*)(p + g + k0);
            pf[2 * a + 1] = *(const f16x8*)(p + g + k0 + 8);
        }
    };
    auto store_tile = [&]() {
#pragma unroll
        for (int a = 0; a < NARR; ++a) {
            *(f16x8*)&stage[a * ARR + lo0] = pf[2 * a + 0];
            *(f16x8*)&stage[a * ARR + lo1] = pf[2 * a + 1];
        }
    };

    load_tile(0);
    for (int it = 0; it < 32; ++it) {
        store_tile();
        __syncthreads();
        if (it + 1 < 32) load_tile((it + 1) << 5);   // prefetch under compute

        f16x8 xh[4], xl[4];
#pragma unroll
        for (int mt = 0; mt < 4; ++mt) {
            const int off = ch8 * CSB + ((mt << 5) + l31) * 8;
            xh[mt] = *(const f16x8*)&stage[0 * ARR + off];
            if constexpr (MODE == 0)
                xl[mt] = *(const f16x8*)&stage[1 * ARR + off];
        }
#pragma unroll
        for (int nt = 0; nt < 2; ++nt) {
            const int boff = ch8 * CSB + (wn + (nt << 5) + l31) * 8;
            if constexpr (MODE == 0) {
                const f16x8 b1h = *(const f16x8*)&stage[2 * ARR + boff];
                const f16x8 b1l = *(const f16x8*)&stage[3 * ARR + boff];
                const f16x8 b2h = *(const f16x8*)&stage[4 * ARR + boff];
                const f16x8 b2l = *(const f16x8*)&stage[5 * ARR + boff];
#pragma unroll
                for (int mt = 0; mt < 4; ++mt) {
                    acc1[mt][nt] = mfma_h(xh[mt], b1h, acc1[mt][nt]);
                    acc1[mt][nt] = mfma_h(xh[mt], b1l, acc1[mt][nt]);
                    acc1[mt][nt] = mfma_h(xl[mt], b1h, acc1[mt][nt]);
                    acc2[mt][nt] = mfma_h(xh[mt], b2h, acc2[mt][nt]);
                    acc2[mt][nt] = mfma_h(xh[mt], b2l, acc2[mt][nt]);
                    acc2[mt][nt] = mfma_h(xl[mt], b2h, acc2[mt][nt]);
                }
            } else {
                const f16x8 b1h = *(const f16x8*)&stage[1 * ARR + boff];
#pragma unroll
                for (int mt = 0; mt < 4; ++mt)
                    acc1[mt][nt] = mfma_h(xh[mt], b1h, acc1[mt][nt]);
            }
        }
        __syncthreads();   // reads done before next store_tile overwrites
    }

    // K-split merge: ws1 writes fp32 partials to LDS (aliasing stage), ws0 adds.
    // Round = one mt (32 rows x 128 cols fp32 = 16 KB <= stage size both modes).
    float* red = (float*)stage;
#pragma unroll
    for (int ai = 0; ai < (MODE == 0 ? 2 : 1); ++ai) {
#pragma unroll
        for (int mt = 0; mt < 4; ++mt) {
            __syncthreads();
            if (ws == 1) {
#pragma unroll
                for (int nt = 0; nt < 2; ++nt)
#pragma unroll
                    for (int r = 0; r < 16; ++r)
                        red[ROWMAP(r, hh) * 128 + wn + (nt << 5) + l31] =
                            (ai == 0) ? acc1[mt][nt][r] : acc2[mt][nt][r];
            }
            __syncthreads();
            if (ws == 0) {
#pragma unroll
                for (int nt = 0; nt < 2; ++nt)
#pragma unroll
                    for (int r = 0; r < 16; ++r) {
                        const float p = red[ROWMAP(r, hh) * 128 + wn + (nt << 5) + l31];
                        if (ai == 0) acc1[mt][nt][r] += p; else acc2[mt][nt][r] += p;
                    }
            }
        }
    }
    if (ws != 0) return;

    // Epilogue (ws0 waves). C/D map: col=lane&31, row=ROWMAP [m74/m101].
#pragma unroll
    for (int nt = 0; nt < 2; ++nt) {
        const int n = n0 + wn + (nt << 5) + l31;
        if constexpr (MODE == 1) {
#pragma unroll
            for (int mt = 0; mt < 4; ++mt)
#pragma unroll
                for (int r = 0; r < 16; ++r) {
                    const int m = m0 + (mt << 5) + ROWMAP(r, hh);
                    Cout[(size_t)m * E_ + n] = acc1[mt][nt][r];
                }
        } else {
            const int hd = n >> 6, d = n & 63;
            const int b = m0 >> 11;             // block never crosses batch
#pragma unroll
            for (int mt = 0; mt < 4; ++mt) {
                u16 vb[16];
#pragma unroll
                for (int r = 0; r < 16; ++r) {
                    const int s = (m0 + (mt << 5) + ROWMAP(r, hh)) & (S_ - 1);
                    const size_t ib = (((size_t)(b * H_ + hd) << 11) + s) * D_ + d;
                    const float kv = acc1[mt][nt][r];   // SC2 already folded
                    const f16 kh = (f16)kv;
                    Khg[ib] = f16bits(kh);
                    Klg[ib] = f16bits((f16)(kv - (float)kh));
                    const f16 vh = (f16)acc2[mt][nt][r];
                    vb[r] = f16bits(vh);
                    Vhg[ib] = vb[r];
                }
                const size_t vtb = ((size_t)(b * H_ + hd) * D_ + d) << 11;
#pragma unroll
                for (int g = 0; g < 4; ++g) {
                    const int s0 = ((m0 + (mt << 5)) & (S_ - 1)) + (g << 3) + (hh << 2);
                    *(uint2*)&Vtg[vtb + s0] =
                        make_uint2(pack2(vb[4 * g], vb[4 * g + 1]),
                                   pack2(vb[4 * g + 2], vb[4 * g + 3]));
                }
            }
        }
    }
}

// ============================================================================
// Attention: logits2 = Ks@V^T, base-2 online softmax, O = P@V. All fp16.
// 512 thr / 8 waves; 256 s-rows/block; wave w owns s in [32w,32w+32).
// St 2-PASS: st += Vh*Ksh + Vh*Ksl (V-lo dropped; fp16 makes this safe:
// logit noise ~0.04 log2 units). A = Vh (LDS), B = Ks hi/lo (regs, invariant).
// PV: C[m=s][n=d], A = P (per-wave LDS, fp16 via pkrtz), B = Vt (staged from
// global pre-transposed). oacc alpha-rescale per C-ROW via LDS (R2 lesson).
// LDS: 2 V arrays (16.6K) + P (33.8K) -> reads 20 b128/tile/wave (was 28).
// ============================================================================
#define CSA 520             // (64+1)*8 u16
#define VA  (8 * CSA)       // one V array: 4160 u16
#define CSP 264             // (32+1)*8 u16
#define PW  (8 * CSP)       // per-wave P: 2112 u16

__global__ __launch_bounds__(512, 2)
void attn_mfma(const u16* __restrict__ Kh, const u16* __restrict__ Kl,
               const u16* __restrict__ Vh, const u16* __restrict__ Vt,
               u16* __restrict__ Obuf)
{
    __shared__ u16 sV[2 * VA];          // [Vh | Vt]
    __shared__ u16 sP[8][PW];
    __shared__ float Alpha[8][32], Linv[8][32];

    const int tid = threadIdx.x;
    const int w = tid >> 6, l31 = tid & 31, hh = (tid >> 5) & 1;
    const int bh = blockIdx.y;
    const int sbase = blockIdx.x * 256 + (w << 5);
    const int sg = sbase + l31;

    // K fragments (SC2 pre-folded): B[n=s][k=d], hi/lo, loop-invariant
    f16x8 kfh[4], kfl[4];
    {
        const size_t kb = ((size_t)bh * S_ + sg) * D_;
#pragma unroll
        for (int ks = 0; ks < 4; ++ks) {
            const int db = (ks << 4) + (hh << 3);
            kfh[ks] = *(const f16x8*)(Kh + kb + db);
            kfl[ks] = *(const f16x8*)(Kl + kb + db);
        }
    }

    f32x16 oacc[2];
#pragma unroll
    for (int r = 0; r < 16; ++r) { oacc[0][r] = 0.f; oacc[1][r] = 0.f; }
    float m_i = -INFINITY, l_i = 0.f;

    const int rr = tid >> 3, cc = tid & 7;     // staging: row 0..63, chunk 0..7
    const size_t gn = ((size_t)bh * S_ + rr) * D_ + (cc << 3);
    const size_t gt = ((size_t)bh * D_ + rr) * S_ + (cc << 3);
    const int slo = cc * CSA + rr * 8;
    u16* P = &sP[w][0];

    f16x8 pv[2];
    auto load_tile = [&](int t0) {
        pv[0] = *(const f16x8*)(Vh + gn + (size_t)t0 * D_);
        pv[1] = *(const f16x8*)(Vt + gt + t0);
    };

    load_tile(0);
    for (int it = 0; it < 32; ++it) {
        *(f16x8*)&sV[slo] = pv[0];
        *(f16x8*)&sV[VA + slo] = pv[1];
        __syncthreads();
        if (it + 1 < 32) load_tile((it + 1) << 6);   // prefetch

        // St[t][s] = sum_d V[t][d]*Ks[s][d]   (2-pass fp16)
        f32x16 st[2];
#pragma unroll
        for (int r = 0; r < 16; ++r) { st[0][r] = 0.f; st[1][r] = 0.f; }
#pragma unroll
        for (int ks = 0; ks < 4; ++ks) {
            const int ch = (ks << 1) + hh;
#pragma unroll
            for (int mt = 0; mt < 2; ++mt) {
                const f16x8 av = *(const f16x8*)&sV[ch * CSA + ((mt << 5) + l31) * 8];
                st[mt] = mfma_h(av, kfh[ks], st[mt]);
                st[mt] = mfma_h(av, kfl[ks], st[mt]);
            }
        }

        // Online softmax (base 2) over t for col s = l31
        float tmax = -INFINITY;
#pragma unroll
        for (int mt = 0; mt < 2; ++mt)
#pragma unroll
            for (int r = 0; r < 16; ++r) tmax = fmaxf(tmax, st[mt][r]);
        tmax = fmaxf(tmax, __shfl_xor(tmax, 32));
        const float mnew = fmaxf(m_i, tmax);
        const float alpha = __builtin_amdgcn_exp2f(m_i - mnew);  // first tile: 0
        m_i = mnew;
        const unsigned long long cmask = __ballot(tmax >= mnew - 30.f);

        if (cmask) {
            float rsum = 0.f;
#pragma unroll
            for (int mt = 0; mt < 2; ++mt)
#pragma unroll
                for (int r = 0; r < 16; ++r) {
                    const float p = __builtin_amdgcn_exp2f(st[mt][r] - mnew);
                    st[mt][r] = p;
                    rsum += p;
                }
            rsum += __shfl_xor(rsum, 32);
            l_i = l_i * alpha + rsum;
        }
        if (__ballot(alpha != 1.0f)) {
            if (hh == 0) Alpha[w][l31] = alpha;
#pragma unroll
            for (int g = 0; g < 4; ++g) {
                const float4 av = *(const float4*)&Alpha[w][(g << 3) + (hh << 2)];
                const float af[4] = {av.x, av.y, av.z, av.w};
#pragma unroll
                for (int q = 0; q < 4; ++q) {
                    oacc[0][(g << 2) + q] *= af[q];
                    oacc[1][(g << 2) + q] *= af[q];
                }
            }
        }
        if (cmask) {
            // P natural [s][t] fp16: reg quad (mt,g) = t = 32mt+8g+4hh+{0..3}
#pragma unroll
            for (int mt = 0; mt < 2; ++mt)
#pragma unroll
                for (int g = 0; g < 4; ++g)
                    *(uint2*)&P[((mt << 2) + g) * CSP + l31 * 8 + (hh << 2)] =
                        make_uint2(pkrtz(st[mt][4 * g], st[mt][4 * g + 1]),
                                   pkrtz(st[mt][4 * g + 2], st[mt][4 * g + 3]));
            // PV: o[s][d] += sum_t P[s][t] * Vt[d][t]
#pragma unroll
            for (int ks = 0; ks < 4; ++ks) {
                const int ch = (ks << 1) + hh;
                const f16x8 pfr = *(const f16x8*)&P[ch * CSP + l31 * 8];
#pragma unroll
                for (int nt = 0; nt < 2; ++nt) {
                    const f16x8 vtf = *(const f16x8*)&sV[VA + ch * CSA + ((nt << 5) + l31) * 8];
                    oacc[nt] = mfma_h(pfr, vtf, oacc[nt]);
                }
            }
        }
        __syncthreads();   // reads done before next tile overwrites sV
    }

    // Epilogue: normalize per C-row, store O fp16 [M,E]
    if (hh == 0) Linv[w][l31] = 1.0f / l_i;
    const int b = bh >> 4;
    const int hd = bh & 15;
    u16* Or = Obuf + ((size_t)b * S_ + sbase) * E_ + (hd << 6);
#pragma unroll
    for (int g = 0; g < 4; ++g) {
        const float4 iv = *(const float4*)&Linv[w][(g << 3) + (hh << 2)];
        const float invs[4] = {iv.x, iv.y, iv.z, iv.w};
#pragma unroll
        for (int nt = 0; nt < 2; ++nt)
#pragma unroll
            for (int q = 0; q < 4; ++q) {
                const int sl = (g << 3) + (hh << 2) + q;
                Or[(size_t)sl * E_ + (nt << 5) + l31] =
                    f16bits((f16)(oacc[nt][(g << 2) + q] * invs[q]));
            }
    }
}

// ============================================================================
// Workspace (~62 MB):
//   0M Xh | 8M Xl (aliased by Obuf after gemm_kv) | 16M Wkh | 18M Wkl
//   20M Wvh | 22M Wvl | 24M Woh | 26M Kh (convert's Wol-junk; fully
//   overwritten by gemm_kv) | 35M Kl | 44M Vh | 53M Vt
// ============================================================================
extern "C" void kernel_launch(void* const* d_in, const int* in_sizes, int n_in,
                              void* d_out, int out_size, void* d_ws, size_t ws_size,
                              hipStream_t stream)
{
    (void)in_sizes; (void)n_in; (void)out_size; (void)ws_size;
    const float* x  = (const float*)d_in[0];
    // d_in[1] = Wq: computed-but-unused in reference; skipped.
    const float* Wk = (const float*)d_in[2];
    const float* Wv = (const float*)d_in[3];
    const float* Wo = (const float*)d_in[4];
    float* out = (float*)d_out;

    char* ws = (char*)d_ws;
    const size_t MB = 1u << 20;
    u16* Xh  = (u16*)(ws + 0 * MB);
    u16* Xl  = (u16*)(ws + 8 * MB);
    u16* Wkh = (u16*)(ws + 16 * MB);
    u16* Wkl = (u16*)(ws + 18 * MB);
    u16* Wvh = (u16*)(ws + 20 * MB);
    u16* Wvl = (u16*)(ws + 22 * MB);
    u16* Woh = (u16*)(ws + 24 * MB);
    u16* Kh  = (u16*)(ws + 26 * MB);
    u16* Kl  = (u16*)(ws + 35 * MB);
    u16* Vh  = (u16*)(ws + 44 * MB);
    u16* Vt  = (u16*)(ws + 53 * MB);
    u16* Obuf = Xl;        // x-lo dead after gemm_kv
    u16* Wol_junk = Kh;    // fully overwritten by gemm_kv before any read

    convert_split<<<7168, 256, 0, stream>>>(x, Wk, Wv, Wo,
                                            Xh, Xl, Wkh, Wkl, Wvh, Wvl, Woh, Wol_junk);
    gemm_f<0><<<dim3(E_ / 128, M_ / 128), 256, 0, stream>>>(
        Xh, Xl, Wkh, Wkl, Wvh, Wvl, Kh, Kl, Vh, Vt, nullptr);
    attn_mfma<<<dim3(S_ / 256, B_ * H_), 512, 0, stream>>>(Kh, Kl, Vh, Vt, Obuf);
    gemm_f<1><<<dim3(E_ / 128, M_ / 128), 256, 0, stream>>>(
        Obuf, Obuf, Woh, Woh, Woh, Woh,
        nullptr, nullptr, nullptr, nullptr, out);
}

// Round 8
// 220.345 us; speedup vs baseline: 1.0857x; 1.0857x over previous
//
#include <hip/hip_runtime.h>
#include <math.h>

// Problem constants (fixed by reference)
#define B_ 2
#define S_ 2048
#define E_ 1024
#define H_ 16
#define D_ 64
#define M_ (B_ * S_)
// HEAD_DIM * -0.5 = -32 (faithful source bug) folded with 1/ln2 (exp2-domain
// softmax). Folded into Wk at convert time.
#define SC2 (-46.166241308446828f)

typedef unsigned short u16;
typedef _Float16 f16;
typedef __attribute__((ext_vector_type(8))) _Float16 f16x8;   // 4 VGPRs
typedef __attribute__((ext_vector_type(2))) __fp16 fp16x2_n;  // builtin ret type
typedef __attribute__((ext_vector_type(16))) float f32x16;    // 32x32 MFMA acc

static __device__ __forceinline__ f32x16 mfma_h(f16x8 a, f16x8 b, f32x16 c) {
    return __builtin_amdgcn_mfma_f32_32x32x16_f16(a, b, c, 0, 0, 0);
}
static __device__ __forceinline__ u16 f16bits(f16 h) {
    union { f16 h; u16 u; } c; c.h = h; return c.u;
}
static __device__ __forceinline__ unsigned pack2(u16 a, u16 b) {
    return (unsigned)a | ((unsigned)b << 16);
}
// One v_cvt_pkrtz_f16_f32: packs two floats to two fp16 (RTZ; P in [0,1]).
static __device__ __forceinline__ unsigned pkrtz(float a, float b) {
    fp16x2_n h = __builtin_amdgcn_cvt_pkrtz(a, b);
    unsigned u; __builtin_memcpy(&u, &h, 4); return u;
}
#define ROWMAP(r, hh) (((r) & 3) + ((((r) >> 2)) << 3) + ((hh) << 2))

// ============================================================================
// One-shot fp32 -> fp16 hi (+ lo-residual where needed). SC2 folded into Wk.
// x, Wk, Wv: hi+lo. Wo: hi only (final GEMM is hi-only).
// ============================================================================
__global__ __launch_bounds__(256)
void convert_split(const float* __restrict__ x, const float* __restrict__ Wk,
                   const float* __restrict__ Wv, const float* __restrict__ Wo,
                   u16* __restrict__ Xh, u16* __restrict__ Xl,
                   u16* __restrict__ Wkh, u16* __restrict__ Wkl,
                   u16* __restrict__ Wvh, u16* __restrict__ Wvl,
                   u16* __restrict__ Woh)
{
    const int blk = blockIdx.x;
    const float* src; u16 *dh, *dl; int base; float sc = 1.0f; bool wantlo = true;
    if (blk < 4096)      { src = x;  dh = Xh;  dl = Xl;  base = blk; }
    else if (blk < 5120) { src = Wk; dh = Wkh; dl = Wkl; base = blk - 4096; sc = SC2; }
    else if (blk < 6144) { src = Wv; dh = Wvh; dl = Wvl; base = blk - 5120; }
    else                 { src = Wo; dh = Woh; dl = Woh; base = blk - 6144; wantlo = false; }
    const size_t off = ((size_t)base * 256 + threadIdx.x) * 4;
    const float4 v = *(const float4*)(src + off);
    const float f[4] = {v.x * sc, v.y * sc, v.z * sc, v.w * sc};
    u16 h4[4], l4[4];
#pragma unroll
    for (int i = 0; i < 4; ++i) {
        const f16 h = (f16)f[i];
        h4[i] = f16bits(h);
        l4[i] = f16bits((f16)(f[i] - (float)h));
    }
    *(uint2*)(dh + off) = make_uint2(pack2(h4[0], h4[1]), pack2(h4[2], h4[3]));
    if (wantlo)
        *(uint2*)(dl + off) = make_uint2(pack2(l4[0], l4[1]), pack2(l4[2], l4[3]));
}

// ============================================================================
// GEMM C = A @ W^T, 32x32x16 fp16 MFMA, hi/lo fp16 inputs.
// MODE 0: fused K+V projection, 3-pass split each (fp32-grade); outputs
//         Kh/Kl (fp16 hi/lo, SC2 pre-folded), Vh [B,H,S,D], Vt [B,H,D,S].
// MODE 1: O @ Wo^T, hi-only, fp32 out [M,E].
// 512 thr / 8 waves, __launch_bounds__(512,2) => <=256 regs/wave => 2
// waves/SIMD (R7 lesson: 16 f32x16 accs = 256 regs -> 1 wave/SIMD -> 86us).
// Wave quadrants 2x2 of 64x64 (acc 128 AGPR for both outputs) + 2-way
// K-SPLIT (ws), fp32 merge via LDS. Per CU/iter: LDS 1728 cyc vs MFMA 1536.
// Register-prefetch of tile k+1. Grid (8,32)=256 blocks = 1/CU, 8 waves/CU.
// ============================================================================
#define CSB 1032            // (128+1)*8 u16 chunk stride (pad -> spread banks)
#define ARR (4 * CSB)       // one staged array (4 ksubs of 8): 4128 u16

template<int MODE>
__global__ __launch_bounds__(512, 2)
void gemm_f(const u16* __restrict__ Ah_, const u16* __restrict__ Al_,
            const u16* __restrict__ Bkh_, const u16* __restrict__ Bkl_,
            const u16* __restrict__ Bvh_, const u16* __restrict__ Bvl_,
            u16* __restrict__ Khg, u16* __restrict__ Klg,
            u16* __restrict__ Vhg, u16* __restrict__ Vtg,
            float* __restrict__ Cout)
{
    constexpr int NARR = (MODE == 0 ? 6 : 2);
    constexpr int SSZ = (NARR * ARR > 16384 ? NARR * ARR : 16384);  // >=32KB (merge)
    __shared__ u16 stage[SSZ];

    const int tid = threadIdx.x;
    const int w = tid >> 6, l31 = tid & 31, hh = (tid >> 5) & 1;
    const int wt = w & 3, ws = w >> 2;          // quadrant / k-split half
    const int wm = (wt >> 1) << 6, wn = (wt & 1) << 6;
    const int m0 = blockIdx.y * 128, n0 = blockIdx.x * 128;
    const int ch8 = (ws << 1) + hh;             // this wave-half's k-subchunk

    const int sr = tid >> 2, sch = tid & 3;     // staging row 0..127, chunk 0..3
    const size_t gA = (size_t)(m0 + sr) * E_ + (sch << 3);
    const size_t gB = (size_t)(n0 + sr) * E_ + (sch << 3);
    const int slo = sch * CSB + sr * 8;

    f32x16 acc1[2][2], acc2[2][2];
#pragma unroll
    for (int mt = 0; mt < 2; ++mt)
#pragma unroll
        for (int nt = 0; nt < 2; ++nt)
#pragma unroll
            for (int r = 0; r < 16; ++r) {
                acc1[mt][nt][r] = 0.f;
                if constexpr (MODE == 0) acc2[mt][nt][r] = 0.f;
            }

    f16x8 pf[NARR];
    auto load_tile = [&](int k0) {
        pf[0] = *(const f16x8*)(Ah_ + gA + k0);
        if constexpr (MODE == 0) {
            pf[1] = *(const f16x8*)(Al_ + gA + k0);
            pf[2] = *(const f16x8*)(Bkh_ + gB + k0);
            pf[3] = *(const f16x8*)(Bkl_ + gB + k0);
            pf[4] = *(const f16x8*)(Bvh_ + gB + k0);
            pf[5] = *(const f16x8*)(Bvl_ + gB + k0);
        } else {
            pf[1] = *(const f16x8*)(Bkh_ + gB + k0);
        }
    };
    auto store_tile = [&]() {
#pragma unroll
        for (int a = 0; a < NARR; ++a)
            *(f16x8*)&stage[a * ARR + slo] = pf[a];
    };

    load_tile(0);
    for (int it = 0; it < 32; ++it) {
        store_tile();
        __syncthreads();
        if (it + 1 < 32) load_tile((it + 1) << 5);   // prefetch under compute

        const int co = ch8 * CSB;
        f16x8 xh[2], xl[2];
#pragma unroll
        for (int mt = 0; mt < 2; ++mt) {
            const int off = co + (wm + (mt << 5) + l31) * 8;
            xh[mt] = *(const f16x8*)&stage[0 * ARR + off];
            if constexpr (MODE == 0)
                xl[mt] = *(const f16x8*)&stage[1 * ARR + off];
        }
#pragma unroll
        for (int nt = 0; nt < 2; ++nt) {
            const int ro = co + (wn + (nt << 5) + l31) * 8;
            if constexpr (MODE == 0) {
                const f16x8 bkh = *(const f16x8*)&stage[2 * ARR + ro];
                const f16x8 bkl = *(const f16x8*)&stage[3 * ARR + ro];
                const f16x8 bvh = *(const f16x8*)&stage[4 * ARR + ro];
                const f16x8 bvl = *(const f16x8*)&stage[5 * ARR + ro];
#pragma unroll
                for (int mt = 0; mt < 2; ++mt) {
                    acc1[mt][nt] = mfma_h(xh[mt], bkh, acc1[mt][nt]);
                    acc1[mt][nt] = mfma_h(xh[mt], bkl, acc1[mt][nt]);
                    acc1[mt][nt] = mfma_h(xl[mt], bkh, acc1[mt][nt]);
                    acc2[mt][nt] = mfma_h(xh[mt], bvh, acc2[mt][nt]);
                    acc2[mt][nt] = mfma_h(xh[mt], bvl, acc2[mt][nt]);
                    acc2[mt][nt] = mfma_h(xl[mt], bvh, acc2[mt][nt]);
                }
            } else {
                const f16x8 bh = *(const f16x8*)&stage[1 * ARR + ro];
#pragma unroll
                for (int mt = 0; mt < 2; ++mt)
                    acc1[mt][nt] = mfma_h(xh[mt], bh, acc1[mt][nt]);
            }
        }
        __syncthreads();   // reads done before next store_tile overwrites
    }

    // K-split merge via LDS (32KB rounds), ws1 -> ws0.
    float* red = (float*)stage;
    constexpr int NR = (MODE == 0 ? 4 : 2);
#pragma unroll
    for (int rd = 0; rd < NR; ++rd) {
        const int mt = rd & 1;
        f32x16 (*A)[2] = (MODE == 0 && rd >= 2) ? acc2 : acc1;
        __syncthreads();
        if (ws == 1) {
#pragma unroll
            for (int nt = 0; nt < 2; ++nt)
#pragma unroll
                for (int r = 0; r < 16; ++r)
                    red[(((wt << 1) + nt) << 10) + (r << 6) + (hh << 5) + l31] = A[mt][nt][r];
        }
        __syncthreads();
        if (ws == 0) {
#pragma unroll
            for (int nt = 0; nt < 2; ++nt)
#pragma unroll
                for (int r = 0; r < 16; ++r)
                    A[mt][nt][r] += red[(((wt << 1) + nt) << 10) + (r << 6) + (hh << 5) + l31];
        }
    }
    if (ws != 0) return;

    // Epilogue (ws0). C/D map: col=lane&31, row=ROWMAP [m74/m101].
#pragma unroll
    for (int nt = 0; nt < 2; ++nt) {
        const int n = n0 + wn + (nt << 5) + l31;
        if constexpr (MODE == 1) {
#pragma unroll
            for (int mt = 0; mt < 2; ++mt)
#pragma unroll
                for (int r = 0; r < 16; ++r) {
                    const int m = m0 + wm + (mt << 5) + ROWMAP(r, hh);
                    Cout[(size_t)m * E_ + n] = acc1[mt][nt][r];
                }
        } else {
            const int hd = n >> 6, d = n & 63;
            const int b = m0 >> 11;             // block never crosses batch
#pragma unroll
            for (int mt = 0; mt < 2; ++mt) {
                u16 vb16[16];
#pragma unroll
                for (int r = 0; r < 16; ++r) {
                    const int s = (m0 + wm + (mt << 5) + ROWMAP(r, hh)) & (S_ - 1);
                    const size_t ib = (((size_t)(b * H_ + hd) << 11) + s) * D_ + d;
                    const float kv = acc1[mt][nt][r];   // SC2 already folded
                    const f16 kh = (f16)kv;
                    Khg[ib] = f16bits(kh);
                    Klg[ib] = f16bits((f16)(kv - (float)kh));
                    const f16 vh = (f16)acc2[mt][nt][r];
                    vb16[r] = f16bits(vh);
                    Vhg[ib] = vb16[r];
                }
                const size_t vtb = ((size_t)(b * H_ + hd) * D_ + d) << 11;
#pragma unroll
                for (int g = 0; g < 4; ++g) {
                    const int s0 = ((m0 + wm + (mt << 5)) & (S_ - 1)) + (g << 3) + (hh << 2);
                    *(uint2*)&Vtg[vtb + s0] =
                        make_uint2(pack2(vb16[4 * g], vb16[4 * g + 1]),
                                   pack2(vb16[4 * g + 2], vb16[4 * g + 3]));
                }
            }
        }
    }
}

// ============================================================================
// Attention: logits2 = Ks@V^T, base-2 online softmax, O = P@V. All fp16.
// 512 thr / 8 waves; 256 s-rows/block; wave w owns s in [32w,32w+32).
// St 2-PASS with DUAL accumulator chains (sta: Vh*Ksh, stb: Vh*Ksl) -> 4
// independent 4-long MFMA chains instead of 2x8 dependent (pipe fill at 2
// waves/SIMD). V-lo dropped (fp16: logit noise ~0.04-0.09 log2, measured
// absmax 0.086 < 0.119). PV: A = P (per-wave LDS, pkrtz), B = Vt (staged
// pre-transposed). alpha rescale per C-ROW via LDS (R2 lesson). Ballot-skip
// of dead tiles.
// ============================================================================
#define CSA 520             // (64+1)*8 u16
#define VA  (8 * CSA)       // one V array: 4160 u16
#define CSP 264             // (32+1)*8 u16
#define PW  (8 * CSP)       // per-wave P: 2112 u16

__global__ __launch_bounds__(512, 2)
void attn_mfma(const u16* __restrict__ Kh, const u16* __restrict__ Kl,
               const u16* __restrict__ Vh, const u16* __restrict__ Vt,
               u16* __restrict__ Obuf)
{
    __shared__ u16 sV[2 * VA];          // [Vh | Vt]
    __shared__ u16 sP[8][PW];
    __shared__ float Alpha[8][32], Linv[8][32];

    const int tid = threadIdx.x;
    const int w = tid >> 6, l31 = tid & 31, hh = (tid >> 5) & 1;
    const int bh = blockIdx.y;
    const int sbase = blockIdx.x * 256 + (w << 5);
    const int sg = sbase + l31;

    // K fragments (SC2 pre-folded): B[n=s][k=d], hi/lo, loop-invariant
    f16x8 kfh[4], kfl[4];
    {
        const size_t kb = ((size_t)bh * S_ + sg) * D_;
#pragma unroll
        for (int ks = 0; ks < 4; ++ks) {
            const int db = (ks << 4) + (hh << 3);
            kfh[ks] = *(const f16x8*)(Kh + kb + db);
            kfl[ks] = *(const f16x8*)(Kl + kb + db);
        }
    }

    f32x16 oacc[2];
#pragma unroll
    for (int r = 0; r < 16; ++r) { oacc[0][r] = 0.f; oacc[1][r] = 0.f; }
    float m_i = -INFINITY, l_i = 0.f;

    const int rr = tid >> 3, cc = tid & 7;     // staging: row 0..63, chunk 0..7
    const size_t gn = ((size_t)bh * S_ + rr) * D_ + (cc << 3);
    const size_t gt = ((size_t)bh * D_ + rr) * S_ + (cc << 3);
    const int slo = cc * CSA + rr * 8;
    u16* P = &sP[w][0];

    f16x8 pv[2];
    auto load_tile = [&](int t0) {
        pv[0] = *(const f16x8*)(Vh + gn + (size_t)t0 * D_);
        pv[1] = *(const f16x8*)(Vt + gt + t0);
    };

    load_tile(0);
    for (int it = 0; it < 32; ++it) {
        *(f16x8*)&sV[slo] = pv[0];
        *(f16x8*)&sV[VA + slo] = pv[1];
        __syncthreads();
        if (it + 1 < 32) load_tile((it + 1) << 6);   // prefetch

        // St[t][s] = sum_d V[t][d]*Ks[s][d]  (2-pass, dual chains)
        f32x16 sta[2], stb[2];
#pragma unroll
        for (int r = 0; r < 16; ++r) {
            sta[0][r] = 0.f; sta[1][r] = 0.f;
            stb[0][r] = 0.f; stb[1][r] = 0.f;
        }
#pragma unroll
        for (int ks = 0; ks < 4; ++ks) {
            const int ch = (ks << 1) + hh;
#pragma unroll
            for (int mt = 0; mt < 2; ++mt) {
                const f16x8 av = *(const f16x8*)&sV[ch * CSA + ((mt << 5) + l31) * 8];
                sta[mt] = mfma_h(av, kfh[ks], sta[mt]);
                stb[mt] = mfma_h(av, kfl[ks], stb[mt]);
            }
        }
#pragma unroll
        for (int mt = 0; mt < 2; ++mt)
#pragma unroll
            for (int r = 0; r < 16; ++r) sta[mt][r] += stb[mt][r];

        // Online softmax (base 2) over t for col s = l31
        float tmax = -INFINITY;
#pragma unroll
        for (int mt = 0; mt < 2; ++mt)
#pragma unroll
            for (int r = 0; r < 16; ++r) tmax = fmaxf(tmax, sta[mt][r]);
        tmax = fmaxf(tmax, __shfl_xor(tmax, 32));
        const float mnew = fmaxf(m_i, tmax);
        const float alpha = __builtin_amdgcn_exp2f(m_i - mnew);  // first tile: 0
        m_i = mnew;
        const unsigned long long cmask = __ballot(tmax >= mnew - 30.f);

        if (cmask) {
            float rsum = 0.f;
#pragma unroll
            for (int mt = 0; mt < 2; ++mt)
#pragma unroll
                for (int r = 0; r < 16; ++r) {
                    const float p = __builtin_amdgcn_exp2f(sta[mt][r] - mnew);
                    sta[mt][r] = p;
                    rsum += p;
                }
            rsum += __shfl_xor(rsum, 32);
            l_i = l_i * alpha + rsum;
        }
        if (__ballot(alpha != 1.0f)) {
            if (hh == 0) Alpha[w][l31] = alpha;
#pragma unroll
            for (int g = 0; g < 4; ++g) {
                const float4 av = *(const float4*)&Alpha[w][(g << 3) + (hh << 2)];
                const float af[4] = {av.x, av.y, av.z, av.w};
#pragma unroll
                for (int q = 0; q < 4; ++q) {
                    oacc[0][(g << 2) + q] *= af[q];
                    oacc[1][(g << 2) + q] *= af[q];
                }
            }
        }
        if (cmask) {
            // P natural [s][t] fp16: reg quad (mt,g) = t = 32mt+8g+4hh+{0..3}
#pragma unroll
            for (int mt = 0; mt < 2; ++mt)
#pragma unroll
                for (int g = 0; g < 4; ++g)
                    *(uint2*)&P[((mt << 2) + g) * CSP + l31 * 8 + (hh << 2)] =
                        make_uint2(pkrtz(sta[mt][4 * g], sta[mt][4 * g + 1]),
                                   pkrtz(sta[mt][4 * g + 2], sta[mt][4 * g + 3]));
            // PV: o[s][d] += sum_t P[s][t] * Vt[d][t]
#pragma unroll
            for (int ks = 0; ks < 4; ++ks) {
                const int ch = (ks << 1) + hh;
                const f16x8 pfr = *(const f16x8*)&P[ch * CSP + l31 * 8];
#pragma unroll
                for (int nt = 0; nt < 2; ++nt) {
                    const f16x8 vtf = *(const f16x8*)&sV[VA + ch * CSA + ((nt << 5) + l31) * 8];
                    oacc[nt] = mfma_h(pfr, vtf, oacc[nt]);
                }
            }
        }
        __syncthreads();   // reads done before next tile overwrites sV
    }

    // Epilogue: normalize per C-row, store O fp16 [M,E]
    if (hh == 0) Linv[w][l31] = 1.0f / l_i;
    const int b = bh >> 4;
    const int hd = bh & 15;
    u16* Or = Obuf + ((size_t)b * S_ + sbase) * E_ + (hd << 6);
#pragma unroll
    for (int g = 0; g < 4; ++g) {
        const float4 iv = *(const float4*)&Linv[w][(g << 3) + (hh << 2)];
        const float invs[4] = {iv.x, iv.y, iv.z, iv.w};
#pragma unroll
        for (int nt = 0; nt < 2; ++nt)
#pragma unroll
            for (int q = 0; q < 4; ++q) {
                const int sl = (g << 3) + (hh << 2) + q;
                Or[(size_t)sl * E_ + (nt << 5) + l31] =
                    f16bits((f16)(oacc[nt][(g << 2) + q] * invs[q]));
            }
    }
}

// ============================================================================
// Workspace (~58 MB):
//   0M Xh | 8M Xl (aliased by Obuf after gemm_kv) | 16M Wkh | 18M Wkl
//   20M Wvh | 22M Wvl | 24M Woh | 26M Kh | 34M Kl | 42M Vh | 50M Vt
// ============================================================================
extern "C" void kernel_launch(void* const* d_in, const int* in_sizes, int n_in,
                              void* d_out, int out_size, void* d_ws, size_t ws_size,
                              hipStream_t stream)
{
    (void)in_sizes; (void)n_in; (void)out_size; (void)ws_size;
    const float* x  = (const float*)d_in[0];
    // d_in[1] = Wq: computed-but-unused in reference; skipped.
    const float* Wk = (const float*)d_in[2];
    const float* Wv = (const float*)d_in[3];
    const float* Wo = (const float*)d_in[4];
    float* out = (float*)d_out;

    char* ws = (char*)d_ws;
    const size_t MB = 1u << 20;
    u16* Xh  = (u16*)(ws + 0 * MB);
    u16* Xl  = (u16*)(ws + 8 * MB);
    u16* Wkh = (u16*)(ws + 16 * MB);
    u16* Wkl = (u16*)(ws + 18 * MB);
    u16* Wvh = (u16*)(ws + 20 * MB);
    u16* Wvl = (u16*)(ws + 22 * MB);
    u16* Woh = (u16*)(ws + 24 * MB);
    u16* Kh  = (u16*)(ws + 26 * MB);
    u16* Kl  = (u16*)(ws + 34 * MB);
    u16* Vh  = (u16*)(ws + 42 * MB);
    u16* Vt  = (u16*)(ws + 50 * MB);
    u16* Obuf = Xl;        // x-lo dead after gemm_kv

    convert_split<<<7168, 256, 0, stream>>>(x, Wk, Wv, Wo,
                                            Xh, Xl, Wkh, Wkl, Wvh, Wvl, Woh);
    gemm_f<0><<<dim3(E_ / 128, M_ / 128), 512, 0, stream>>>(
        Xh, Xl, Wkh, Wkl, Wvh, Wvl, Kh, Kl, Vh, Vt, nullptr);
    attn_mfma<<<dim3(S_ / 256, B_ * H_), 512, 0, stream>>>(Kh, Kl, Vh, Vt, Obuf);
    gemm_f<1><<<dim3(E_ / 128, M_ / 128), 512, 0, stream>>>(
        Obuf, Obuf, Woh, Woh, Woh, Woh,
        nullptr, nullptr, nullptr, nullptr, out);
}